// Round 10
// baseline (415.490 us; speedup 1.0000x reference)
//
#include <hip/hip_runtime.h>
#include <math.h>

#define SDIM 1024
#define COUT 256

#define EPSV     1e-4f
#define SILU_INV 1.6778523489932886f   // 1/0.596
#define MPA      0.9191450300180579f   // 0.7/sqrt(0.58)
#define MPB      0.3939192985791677f   // 0.3/sqrt(0.58)
#define LOG2E    1.4426950408889634f

typedef short s16x8 __attribute__((ext_vector_type(8)));
typedef float f32x4 __attribute__((ext_vector_type(4)));
typedef unsigned short ushort_t;

#if __has_builtin(__builtin_amdgcn_exp2f)
#define EXP2F __builtin_amdgcn_exp2f
#else
#define EXP2F exp2f
#endif

__device__ inline ushort_t f2bs(float f) {
    unsigned u = __float_as_uint(f);
    u += 0x7fffu + ((u >> 16) & 1u);        // round-nearest-even
    return (ushort_t)(u >> 16);
}
__device__ inline float silu_mp(float v) { return v * SILU_INV / (1.f + __expf(-v)); }

union F8 { s16x8 v; uint4 q; };
__device__ inline s16x8 ld16(const ushort_t* p) {   // 16B-aligned (global or LDS)
    F8 r; r.q = *(const uint4*)p; return r.v;
}

// async global -> LDS, 16 B per lane. LDS dst = wave-uniform base + lane*16.
typedef const __attribute__((address_space(1))) unsigned int* gas_ptr;
typedef __attribute__((address_space(3))) unsigned int* las_ptr;
__device__ inline void gld16(const void* g, void* l) {
    __builtin_amdgcn_global_load_lds((gas_ptr)g, (las_ptr)l, 16, 0, 0);
}

// ---------------- fused prologue: all weight norms + x transpose + zbuf fill.
// blocks: [0,256) wskip | [256,512) res0 | [512,768) res1 | [768,1536) qkv |
//         [1536,1792) proj | [1792,2560) prep_xT | 2560 zfill
__global__ __launch_bounds__(256) void prep_all(
    const float* __restrict__ w_skip, const float* __restrict__ w_res0,
    const float* __restrict__ w_res1, const float* __restrict__ w_qkv,
    const float* __restrict__ w_proj, const float* __restrict__ x,
    ushort_t* wskip_bf, ushort_t* wres0_bf, ushort_t* wres1_bf,
    ushort_t* wqkv_bf, ushort_t* wproj_bf, ushort_t* xT, uint4* zbuf)
{
    __shared__ float T[64 * 65];
    const int b = blockIdx.x, tid = threadIdx.x;

    if (b >= 2560) {                     // zfill
        if (tid < 64) zbuf[tid] = make_uint4(0u, 0u, 0u, 0u);
        return;
    }
    if (b >= 1792) {                     // prep_xT: [n][192][1024] f32 -> [n][1024][192] bf16
        int b2 = b - 1792;
        int n = b2 / 48, rem = b2 % 48;
        int ci0 = (rem / 16) * 64, s0 = (rem & 15) * 64;
#pragma unroll
        for (int i = 0; i < 16; i++) {
            int ch = tid + i * 256; int row = ch >> 6, cc = ch & 63;
            T[row * 65 + cc] = x[((size_t)n * 192 + ci0 + row) * SDIM + s0 + cc];
        }
        __syncthreads();
#pragma unroll
        for (int i = 0; i < 2; i++) {
            int ch = tid + i * 256; int srow = ch >> 3, c8 = ch & 7;
            ushort_t tmp[8];
#pragma unroll
            for (int j = 0; j < 8; j++) tmp[j] = f2bs(T[(c8 * 8 + j) * 65 + srow]);
            *(uint4*)(xT + ((size_t)n * SDIM + s0 + srow) * 192 + ci0 + c8 * 8) = *(uint4*)tmp;
        }
        return;
    }
    // weight-norm branches
    const float* src; ushort_t* dst; int fanin, mode, o;
    if      (b < 256)  { src = w_skip; dst = wskip_bf; fanin = 192;  mode = 0; o = b; }
    else if (b < 512)  { src = w_res0; dst = wres0_bf; fanin = 2304; mode = 1; o = b - 256; }
    else if (b < 768)  { src = w_res1; dst = wres1_bf; fanin = 2304; mode = 1; o = b - 512; }
    else if (b < 1536) { src = w_qkv;  dst = wqkv_bf;  fanin = 256;  mode = 2; o = b - 768; }
    else               { src = w_proj; dst = wproj_bf; fanin = 256;  mode = 0; o = b - 1536; }

    const float* row = src + (size_t)o * fanin;
    float ss = 0.f;
    for (int i = tid; i < fanin; i += 256) { float v = row[i]; ss += v * v; }
    for (int off = 32; off >= 1; off >>= 1) ss += __shfl_down(ss, off);
    int lane = tid & 63, wv = tid >> 6;
    if (lane == 0) T[wv] = ss;
    __syncthreads();
    float tot = T[0] + T[1] + T[2] + T[3];
    float scale = 1.0f / (EPSV * sqrtf((float)fanin) + sqrtf(tot));
    int orow = o;
    if (mode == 2) { int h = o / 192, rem = o % 192; orow = (rem % 3) * 256 + h * 64 + rem / 3; }
    for (int i = tid; i < fanin; i += 256) {
        int kd = i;
        if (mode == 1) { int ci = i / 9; int r9 = i - ci * 9; kd = r9 * 256 + ci; }
        dst[(size_t)orow * fanin + kd] = f2bs(row[i] * scale);
    }
}

// ---------------- c = emb @ mp_weight(w_emb, gain)^T + 1  (norm fused per thread)
__global__ __launch_bounds__(256) void emb_mm(const float* __restrict__ emb,
                                              const float* __restrict__ w_emb,
                                              const float* __restrict__ gain_ptr,
                                              float* __restrict__ cvec)
{
    int n = blockIdx.x;
    int co = threadIdx.x;
    const float* e  = emb   + (size_t)n * 768;
    const float* wr = w_emb + (size_t)co * 768;
    float ss = 0.f, dot = 0.f;
    for (int i = 0; i < 768; i++) {
        float wv = wr[i];
        ss  = fmaf(wv, wv, ss);
        dot = fmaf(e[i], wv, dot);
    }
    float scale = gain_ptr[0] / (EPSV * sqrtf(768.0f) + sqrtf(ss));
    cvec[n * COUT + co] = dot * scale + 1.0f;
}

// ---------------- fused: x1 = conv1x1(x, wskip); xn = pix_norm(x1); sxT = silu(xn)
__global__ __launch_bounds__(256, 2) void skip_fused(const ushort_t* __restrict__ Wp,
                                                     const ushort_t* __restrict__ xT,
                                                     float* __restrict__ xn,
                                                     ushort_t* __restrict__ sxT)
{
    const int n = blockIdx.z, s0 = blockIdx.x * 32;
    const int tid = threadIdx.x, w = tid >> 6, lane = tid & 63;
    const int tx = lane & 15, quad = lane >> 4;

    __shared__ ushort_t As[256 * 72];
    __shared__ ushort_t Bs[32 * 72];
    __shared__ float csum[4][32];

    f32x4 acc[4][2];
#pragma unroll
    for (int a = 0; a < 4; a++)
#pragma unroll
        for (int b = 0; b < 2; b++) acc[a][b] = (f32x4){0.f, 0.f, 0.f, 0.f};

    for (int k0 = 0; k0 < 192; k0 += 64) {
        __syncthreads();
#pragma unroll
        for (int i = 0; i < 8; i++) {
            int ch = tid + i * 256; int row = ch >> 3, c8 = ch & 7;
            *(uint4*)&As[row * 72 + c8 * 8] = *(const uint4*)(Wp + (size_t)row * 192 + k0 + c8 * 8);
        }
        {
            int row = tid >> 3, c8 = tid & 7;
            *(uint4*)&Bs[row * 72 + c8 * 8] =
                *(const uint4*)(xT + ((size_t)n * SDIM + s0 + row) * 192 + k0 + c8 * 8);
        }
        __syncthreads();
#pragma unroll
        for (int kc = 0; kc < 2; kc++) {
            s16x8 af[4], bf_[2];
#pragma unroll
            for (int mt = 0; mt < 4; mt++) af[mt] = ld16(&As[(w * 64 + mt * 16 + tx) * 72 + kc * 32 + quad * 8]);
#pragma unroll
            for (int nt = 0; nt < 2; nt++) bf_[nt] = ld16(&Bs[(nt * 16 + tx) * 72 + kc * 32 + quad * 8]);
#pragma unroll
            for (int mt = 0; mt < 4; mt++)
#pragma unroll
                for (int nt = 0; nt < 2; nt++)
                    acc[mt][nt] = __builtin_amdgcn_mfma_f32_16x16x32_bf16(af[mt], bf_[nt], acc[mt][nt], 0, 0, 0);
        }
    }

#pragma unroll
    for (int nt = 0; nt < 2; nt++) {
        float s2 = 0.f;
#pragma unroll
        for (int mt = 0; mt < 4; mt++)
#pragma unroll
            for (int r = 0; r < 4; r++) s2 = fmaf(acc[mt][nt][r], acc[mt][nt][r], s2);
        s2 += __shfl_xor(s2, 16); s2 += __shfl_xor(s2, 32);
        if (quad == 0) csum[w][nt * 16 + tx] = s2;
    }
    __syncthreads();
    float f[2];
#pragma unroll
    for (int nt = 0; nt < 2; nt++) {
        int col = nt * 16 + tx;
        float tot = csum[0][col] + csum[1][col] + csum[2][col] + csum[3][col];
        f[nt] = 1.f / (EPSV + sqrtf(tot) * 0.0625f);
    }
    ushort_t* Ls = As;                      // [32 s][264 co]
    float* xb = xn + (size_t)n * COUT * SDIM;
#pragma unroll
    for (int mt = 0; mt < 4; mt++)
#pragma unroll
        for (int r = 0; r < 4; r++) {
            int co = w * 64 + mt * 16 + quad * 4 + r;
#pragma unroll
            for (int nt = 0; nt < 2; nt++) {
                int sp = s0 + nt * 16 + tx;
                float v = acc[mt][nt][r] * f[nt];
                xb[(size_t)co * SDIM + sp] = v;
                Ls[(nt * 16 + tx) * 264 + co] = f2bs(silu_mp(v));
            }
        }
    __syncthreads();
#pragma unroll
    for (int i = 0; i < 4; i++) {
        int ch = tid + i * 256; int row = ch >> 5, c32 = ch & 31;
        *(uint4*)(sxT + ((size_t)n * SDIM + s0 + row) * 256 + c32 * 8) = *(uint4*)&Ls[row * 264 + c32 * 8];
    }
}

// ---------------- bf16 MFMA conv GEMM, LDS-FREE K-loop: all fragments read
// directly from global (L1/L2-served), no barriers, no staging. 128co x 64s
// tile, waves 2x2 (wave 64co x 32s), K-chunks of 32 (quad*8 within chunk).
// LDS used only for the epilogue repack.
// MODE 1: res0 -> *cvec, silu, OutT bf16 [n][1024][256] (transposed)
// MODE 2: res1 -> x2 = MPA*xn+MPB*acc; xn fp32 in place; OutT bf16 [n][1024][256]
// MODE 3: proj -> Outf = clip(MPA*RX+MPB*acc) fp32 [n][256][1024]
// MODE 4: qkv  -> fused 64-ch norm; q,k (co0<512) -> OutT = qkT[n][1024][512]
//                 (q scaled 0.125*log2e); v (co0>=512) -> Vout = vbuf[n][256][1024]
template<int KDIM, bool GATHER3, int MODE>
__global__ __launch_bounds__(256, 2) void gemm_direct(const ushort_t* __restrict__ Wp,
                                                      const ushort_t* __restrict__ Bsrc,
                                                      const ushort_t* __restrict__ zbuf,
                                                      float* RX, float* Outf,
                                                      ushort_t* OutT, ushort_t* Vout,
                                                      const float* __restrict__ cvec)
{
    const int n = blockIdx.z, co0 = blockIdx.y * 128, s0 = blockIdx.x * 64;
    const int tid = threadIdx.x, w = tid >> 6, lane = tid & 63;
    const int tx = lane & 15, quad = lane >> 4;
    const int wm = w >> 1, ws = w & 1;

    __shared__ ushort_t Ls[9216];           // epilogue repack only

    const ushort_t* bn = Bsrc + (size_t)n * SDIM * 256;
    // this lane's A rows (fixed across K)
    const ushort_t* arow[4];
#pragma unroll
    for (int mt = 0; mt < 4; mt++)
        arow[mt] = Wp + (size_t)(co0 + wm * 64 + mt * 16 + tx) * KDIM;
    // this lane's B pixels (fixed across K)
    const int pix0 = s0 + ws * 32 + tx;

    f32x4 acc[4][2];
#pragma unroll
    for (int a = 0; a < 4; a++)
#pragma unroll
        for (int b = 0; b < 2; b++) acc[a][b] = (f32x4){0.f, 0.f, 0.f, 0.f};

    constexpr int NKC = KDIM / 32;
#pragma unroll 4
    for (int kcg = 0; kcg < NKC; kcg++) {
        const int k = kcg * 32 + quad * 8;
        s16x8 af[4], bfv[2];
#pragma unroll
        for (int mt = 0; mt < 4; mt++) af[mt] = ld16(arow[mt] + k);
        if (GATHER3) {
            const int seg = k >> 8;                 // uniform within chunk (256-aligned segs)
            const int ci  = k & 255;
            const int s3  = seg / 3;
            const int dy  = s3 - 1, dx = seg - s3 * 3 - 1;
#pragma unroll
            for (int nt = 0; nt < 2; nt++) {
                int pix = pix0 + nt * 16;
                int h = (pix >> 5) + dy, wx = (pix & 31) + dx;
                bool valid = ((unsigned)h < 32u) && ((unsigned)wx < 32u);
                const ushort_t* g = valid ? (bn + (size_t)((h << 5) + wx) * 256 + ci) : zbuf;
                bfv[nt] = ld16(g);
            }
        } else {
#pragma unroll
            for (int nt = 0; nt < 2; nt++)
                bfv[nt] = ld16(bn + (size_t)(pix0 + nt * 16) * 256 + k);
        }
#pragma unroll
        for (int mt = 0; mt < 4; mt++)
#pragma unroll
            for (int nt = 0; nt < 2; nt++)
                acc[mt][nt] = __builtin_amdgcn_mfma_f32_16x16x32_bf16(af[mt], bfv[nt], acc[mt][nt], 0, 0, 0);
    }

    if (MODE == 4) {
        float scl[2];
#pragma unroll
        for (int nt = 0; nt < 2; nt++) {
            float s2 = 0.f;
#pragma unroll
            for (int mt = 0; mt < 4; mt++)
#pragma unroll
                for (int r = 0; r < 4; r++) s2 = fmaf(acc[mt][nt][r], acc[mt][nt][r], s2);
            s2 += __shfl_xor(s2, 16); s2 += __shfl_xor(s2, 32);
            float fac = (co0 < 256) ? (0.125f * LOG2E) : 1.0f;
            scl[nt] = fac / (EPSV + sqrtf(s2) * 0.125f);
        }
#pragma unroll
        for (int mt = 0; mt < 4; mt++)
#pragma unroll
            for (int nt = 0; nt < 2; nt++)
#pragma unroll
                for (int r = 0; r < 4; r++) acc[mt][nt][r] *= scl[nt];

        if (co0 < 512) {      // q,k: transposed -> qkT[n][s][512]
#pragma unroll
            for (int mt = 0; mt < 4; mt++)
#pragma unroll
                for (int nt = 0; nt < 2; nt++)
#pragma unroll
                    for (int r = 0; r < 4; r++)
                        Ls[(ws * 32 + nt * 16 + tx) * 136 + wm * 64 + mt * 16 + quad * 4 + r] = f2bs(acc[mt][nt][r]);
            __syncthreads();
#pragma unroll
            for (int i = 0; i < 4; i++) {
                int ch = tid + i * 256; int row = ch >> 4, c16 = ch & 15;
                *(uint4*)(OutT + ((size_t)n * SDIM + s0 + row) * 512 + co0 + c16 * 8) = *(uint4*)&Ls[row * 136 + c16 * 8];
            }
        } else {              // v: [co][s] -> vbuf[n][256][1024]
#pragma unroll
            for (int mt = 0; mt < 4; mt++)
#pragma unroll
                for (int nt = 0; nt < 2; nt++)
#pragma unroll
                    for (int r = 0; r < 4; r++)
                        Ls[(wm * 64 + mt * 16 + quad * 4 + r) * 72 + ws * 32 + nt * 16 + tx] = f2bs(acc[mt][nt][r]);
            __syncthreads();
#pragma unroll
            for (int i = 0; i < 4; i++) {
                int ch = tid + i * 256; int row = ch >> 3, c8 = ch & 7;
                *(uint4*)(Vout + ((size_t)n * 256 + (co0 - 512) + row) * SDIM + s0 + c8 * 8) = *(uint4*)&Ls[row * 72 + c8 * 8];
            }
        }
    }
    if (MODE == 1) {
        float cm[4][4];
#pragma unroll
        for (int mt = 0; mt < 4; mt++)
#pragma unroll
            for (int r = 0; r < 4; r++)
                cm[mt][r] = cvec[n * COUT + co0 + wm * 64 + mt * 16 + quad * 4 + r];
#pragma unroll
        for (int mt = 0; mt < 4; mt++)
#pragma unroll
            for (int nt = 0; nt < 2; nt++)
#pragma unroll
                for (int r = 0; r < 4; r++) {
                    float v = silu_mp(acc[mt][nt][r] * cm[mt][r]);
                    Ls[(ws * 32 + nt * 16 + tx) * 136 + wm * 64 + mt * 16 + quad * 4 + r] = f2bs(v);
                }
        __syncthreads();
#pragma unroll
        for (int i = 0; i < 4; i++) {
            int ch = tid + i * 256; int row = ch >> 4, c16 = ch & 15;
            *(uint4*)(OutT + ((size_t)n * SDIM + s0 + row) * 256 + co0 + c16 * 8) = *(uint4*)&Ls[row * 136 + c16 * 8];
        }
    }
    if (MODE == 2) {
#pragma unroll
        for (int mt = 0; mt < 4; mt++)
#pragma unroll
            for (int r = 0; r < 4; r++) {
                int col = wm * 64 + mt * 16 + quad * 4 + r;
                float* xp = RX + ((size_t)n * COUT + co0 + col) * SDIM + s0 + ws * 32;
#pragma unroll
                for (int nt = 0; nt < 2; nt++) {
                    float v = MPA * xp[nt * 16 + tx] + MPB * acc[mt][nt][r];
                    xp[nt * 16 + tx] = v;
                    Ls[(ws * 32 + nt * 16 + tx) * 136 + col] = f2bs(v);
                }
            }
        __syncthreads();
#pragma unroll
        for (int i = 0; i < 4; i++) {
            int ch = tid + i * 256; int row = ch >> 4, c16 = ch & 15;
            *(uint4*)(OutT + ((size_t)n * SDIM + s0 + row) * 256 + co0 + c16 * 8) = *(uint4*)&Ls[row * 136 + c16 * 8];
        }
    }
    if (MODE == 3) {
#pragma unroll
        for (int mt = 0; mt < 4; mt++)
#pragma unroll
            for (int r = 0; r < 4; r++) {
                int co = co0 + wm * 64 + mt * 16 + quad * 4 + r;
                const float* xp = RX + ((size_t)n * COUT + co) * SDIM + s0 + ws * 32;
                float* op = Outf + ((size_t)n * COUT + co) * SDIM + s0 + ws * 32;
#pragma unroll
                for (int nt = 0; nt < 2; nt++) {
                    float v = MPA * xp[nt * 16 + tx] + MPB * acc[mt][nt][r];
                    op[nt * 16 + tx] = fminf(fmaxf(v, -256.f), 256.f);
                }
            }
    }
}

// ---------------- MFMA flash attention, glds-dbuf K/V staging + pipelined P.
// Block = 128 q (4 waves x 32 q), grid (8, head, n) = 512 blocks -> 2 blocks/CU.
__global__ __launch_bounds__(256, 2) void attn_mfma(const ushort_t* __restrict__ qkT,
                                                    const ushort_t* __restrict__ vbuf,
                                                    ushort_t* __restrict__ aT)
{
    const int n = blockIdx.z, head = blockIdx.y, q0 = blockIdx.x * 128;
    const int tid = threadIdx.x, w = tid >> 6, lane = tid & 63;
    const int tx = lane & 15, quad = lane >> 4;
    const int l8 = lane & 7, ld = lane >> 3;
    const int swz = (l8 ^ ld) * 8;

    __shared__ ushort_t Kst[2][4096];   // [stage][64 key][64 c]
    __shared__ ushort_t Vst[2][4096];   // [stage][64 c][64 key]
    __shared__ ushort_t Pw[8][2048];    // [wave*2+stage][32 q][64 k] swizzled / O stage

    const size_t nb = (size_t)n * SDIM;
    const int qw = q0 + w * 32;
    const ushort_t* kg = qkT + nb * 512 + 256 + head * 64;
    const ushort_t* vg = vbuf + ((size_t)n * 256 + head * 64) * SDIM;

    auto stage = [&](int p, int k0) {
#pragma unroll
        for (int j = 0; j < 2; j++) {
            int row0 = w * 16 + j * 8;
            gld16(kg + (size_t)(k0 + row0 + ld) * 512 + swz, &Kst[p][row0 * 64]);
            gld16(vg + (size_t)(row0 + ld) * SDIM + k0 + swz, &Vst[p][row0 * 64]);
        }
    };
    auto pv_step = [&](int pb, f32x4 (&acco)[2][4]) {
        const ushort_t* Pp = Pw[w * 2 + pb];
#pragma unroll
        for (int kc = 0; kc < 2; kc++) {
            int koff = ((kc * 4 + quad) ^ (tx & 7)) * 8;
            s16x8 pf[2];
#pragma unroll
            for (int mt = 0; mt < 2; mt++)
                pf[mt] = ld16(&Pp[(mt * 16 + tx) * 64 + koff]);
#pragma unroll
            for (int nt = 0; nt < 4; nt++) {
                s16x8 vf = ld16(&Vst[pb][(nt * 16 + tx) * 64 + koff]);
#pragma unroll
                for (int mt = 0; mt < 2; mt++)
                    acco[mt][nt] = __builtin_amdgcn_mfma_f32_16x16x32_bf16(
                        pf[mt], vf, acco[mt][nt], 0, 0, 0);
            }
        }
    };

    s16x8 qf[2][2];
#pragma unroll
    for (int mt = 0; mt < 2; mt++)
#pragma unroll
        for (int kc = 0; kc < 2; kc++)
            qf[mt][kc] = ld16(qkT + (nb + qw + mt * 16 + tx) * 512 + head * 64 + kc * 32 + quad * 8);

    f32x4 acco[2][4];
    float lpart[2][4];
#pragma unroll
    for (int mt = 0; mt < 2; mt++)
#pragma unroll
        for (int nt = 0; nt < 4; nt++) acco[mt][nt] = (f32x4){0.f, 0.f, 0.f, 0.f};
#pragma unroll
    for (int mt = 0; mt < 2; mt++)
#pragma unroll
        for (int r = 0; r < 4; r++) lpart[mt][r] = 0.f;

    stage(0, 0);

    for (int kt = 0; kt < 16; kt++) {
        int p = kt & 1;
        if (kt > 0) pv_step(p ^ 1, acco);
        __syncthreads();
        if (kt < 15) stage(p ^ 1, (kt + 1) * 64);

        f32x4 accs[2][4];
#pragma unroll
        for (int mt = 0; mt < 2; mt++)
#pragma unroll
            for (int nt = 0; nt < 4; nt++) accs[mt][nt] = (f32x4){0.f, 0.f, 0.f, 0.f};
#pragma unroll
        for (int kc = 0; kc < 2; kc++) {
            int koff = ((kc * 4 + quad) ^ (tx & 7)) * 8;
#pragma unroll
            for (int nt = 0; nt < 4; nt++) {
                s16x8 kf = ld16(&Kst[p][(nt * 16 + tx) * 64 + koff]);
#pragma unroll
                for (int mt = 0; mt < 2; mt++)
                    accs[mt][nt] = __builtin_amdgcn_mfma_f32_16x16x32_bf16(
                        qf[mt][kc], kf, accs[mt][nt], 0, 0, 0);
            }
        }
#pragma unroll
        for (int mt = 0; mt < 2; mt++)
#pragma unroll
            for (int r = 0; r < 4; r++) {
                int row = mt * 16 + quad * 4 + r;
                int rx = row & 7;
#pragma unroll
                for (int nt = 0; nt < 4; nt++) {
                    float pv = EXP2F(accs[mt][nt][r]);
                    lpart[mt][r] += pv;
                    int slot = (nt * 2 + (tx >> 3)) ^ rx;
                    Pw[w * 2 + p][row * 64 + slot * 8 + (tx & 7)] = f2bs(pv);
                }
            }
    }
    asm volatile("s_waitcnt lgkmcnt(0)" ::: "memory");
    pv_step(1, acco);

    float inv[2][4];
#pragma unroll
    for (int mt = 0; mt < 2; mt++)
#pragma unroll
        for (int r = 0; r < 4; r++) {
            float l = lpart[mt][r];
            l += __shfl_xor(l, 1); l += __shfl_xor(l, 2);
            l += __shfl_xor(l, 4); l += __shfl_xor(l, 8);
            inv[mt][r] = 1.0f / l;
        }

#pragma unroll
    for (int mt = 0; mt < 2; mt++)
#pragma unroll
        for (int r = 0; r < 4; r++) {
            int row = mt * 16 + quad * 4 + r;
            int rx = row & 7;
#pragma unroll
            for (int nt = 0; nt < 4; nt++) {
                int slot = (nt * 2 + (tx >> 3)) ^ rx;
                Pw[w * 2][row * 64 + slot * 8 + (tx & 7)] = f2bs(acco[mt][nt][r] * inv[mt][r]);
            }
        }
    asm volatile("s_waitcnt lgkmcnt(0)" ::: "memory");
    ushort_t* dst = aT + (nb + qw) * 256 + head * 64;
#pragma unroll
    for (int i = 0; i < 4; i++) {
        int ch = lane + i * 64; int row = ch >> 3, c8 = ch & 7;
        *(uint4*)(dst + (size_t)row * 256 + c8 * 8) = *(uint4*)&Pw[w * 2][row * 64 + (c8 ^ (row & 7)) * 8];
    }
}

extern "C" void kernel_launch(void* const* d_in, const int* in_sizes, int n_in,
                              void* d_out, int out_size, void* d_ws, size_t ws_size,
                              hipStream_t stream)
{
    const float* x      = (const float*)d_in[0];
    const float* emb    = (const float*)d_in[1];
    const float* w_skip = (const float*)d_in[2];
    const float* w_res0 = (const float*)d_in[3];
    const float* w_res1 = (const float*)d_in[4];
    const float* w_emb  = (const float*)d_in[5];
    const float* e_gain = (const float*)d_in[6];
    const float* w_qkv  = (const float*)d_in[7];
    const float* w_proj = (const float*)d_in[8];
    float* out = (float*)d_out;

    char* p = (char*)d_ws;
    auto alloc = [&](size_t bytes) { void* r = (void*)p; p += (bytes + 255) & ~(size_t)255; return r; };
    ushort_t* wskip_bf = (ushort_t*)alloc(256 * 192 * 2);
    ushort_t* wres0_bf = (ushort_t*)alloc(256 * 2304 * 2);
    ushort_t* wres1_bf = (ushort_t*)alloc(256 * 2304 * 2);
    ushort_t* wqkv_bf  = (ushort_t*)alloc(768 * 256 * 2);
    ushort_t* wproj_bf = (ushort_t*)alloc(256 * 256 * 2);
    float*    cvec     = (float*)alloc(16 * 256 * 4);
    ushort_t* zbuf     = (ushort_t*)alloc(1024);
    ushort_t* xT   = (ushort_t*)alloc((size_t)16 * 1024 * 192 * 2);
    ushort_t* sxT  = (ushort_t*)alloc((size_t)16 * 1024 * 256 * 2);
    ushort_t* ysT  = (ushort_t*)alloc((size_t)16 * 1024 * 256 * 2);
    ushort_t* x2T  = (ushort_t*)alloc((size_t)16 * 1024 * 256 * 2);
    ushort_t* aT   = (ushort_t*)alloc((size_t)16 * 1024 * 256 * 2);
    float*    xn   = (float*)alloc((size_t)16 * 256 * 1024 * 4);
    ushort_t* qkT  = (ushort_t*)alloc((size_t)16 * 1024 * 512 * 2);
    ushort_t* vbuf = (ushort_t*)alloc((size_t)16 * 256 * 1024 * 2);

    prep_all<<<2561, 256, 0, stream>>>(w_skip, w_res0, w_res1, w_qkv, w_proj, x,
                                       wskip_bf, wres0_bf, wres1_bf, wqkv_bf, wproj_bf,
                                       xT, (uint4*)zbuf);
    emb_mm<<<16, 256, 0, stream>>>(emb, w_emb, e_gain, cvec);

    skip_fused<<<dim3(32, 1, 16), 256, 0, stream>>>(wskip_bf, xT, xn, sxT);
    gemm_direct<2304, true, 1><<<dim3(16, 2, 16), 256, 0, stream>>>(wres0_bf, sxT, zbuf, nullptr, nullptr, ysT, nullptr, cvec);
    gemm_direct<2304, true, 2><<<dim3(16, 2, 16), 256, 0, stream>>>(wres1_bf, ysT, zbuf, xn, nullptr, x2T, nullptr, nullptr);
    gemm_direct<256, false, 4><<<dim3(16, 6, 16), 256, 0, stream>>>(wqkv_bf, x2T, zbuf, nullptr, nullptr, qkT, vbuf, nullptr);
    attn_mfma<<<dim3(8, 4, 16), 256, 0, stream>>>(qkT, vbuf, aT);
    gemm_direct<256, false, 3><<<dim3(16, 2, 16), 256, 0, stream>>>(wproj_bf, aT, zbuf, xn, out, nullptr, nullptr, nullptr);
}

// Round 11
// 243.816 us; speedup vs baseline: 1.7041x; 1.7041x over previous
//
#include <hip/hip_runtime.h>
#include <math.h>

#define SDIM 1024
#define COUT 256

#define EPSV     1e-4f
#define SILU_INV 1.6778523489932886f   // 1/0.596
#define MPA      0.9191450300180579f   // 0.7/sqrt(0.58)
#define MPB      0.3939192985791677f   // 0.3/sqrt(0.58)
#define LOG2E    1.4426950408889634f

typedef short s16x8 __attribute__((ext_vector_type(8)));
typedef float f32x4 __attribute__((ext_vector_type(4)));
typedef unsigned short ushort_t;

#if __has_builtin(__builtin_amdgcn_exp2f)
#define EXP2F __builtin_amdgcn_exp2f
#else
#define EXP2F exp2f
#endif

__device__ inline ushort_t f2bs(float f) {
    unsigned u = __float_as_uint(f);
    u += 0x7fffu + ((u >> 16) & 1u);        // round-nearest-even
    return (ushort_t)(u >> 16);
}
__device__ inline float silu_mp(float v) { return v * SILU_INV / (1.f + __expf(-v)); }

union F8 { s16x8 v; uint4 q; };
__device__ inline s16x8 ld16(const ushort_t* p) {   // 16B-aligned (global or LDS)
    F8 r; r.q = *(const uint4*)p; return r.v;
}

// async global -> LDS, 16 B per lane. LDS dst = wave-uniform base + lane*16.
typedef const __attribute__((address_space(1))) unsigned int* gas_ptr;
typedef __attribute__((address_space(3))) unsigned int* las_ptr;
__device__ inline void gld16(const void* g, void* l) {
    __builtin_amdgcn_global_load_lds((gas_ptr)g, (las_ptr)l, 16, 0, 0);
}

// ---------------- fused prologue: weight norms + x transpose + zbuf + emb_mm.
// blocks: [0,256) wskip | [256,512) res0 | [512,768) res1 | [768,1536) qkv |
//         [1536,1792) proj | [1792,2560) prep_xT | 2560 zfill | [2561,2577) emb
__global__ __launch_bounds__(256) void prep_all(
    const float* __restrict__ w_skip, const float* __restrict__ w_res0,
    const float* __restrict__ w_res1, const float* __restrict__ w_qkv,
    const float* __restrict__ w_proj, const float* __restrict__ x,
    const float* __restrict__ emb, const float* __restrict__ w_emb,
    const float* __restrict__ gain_ptr, float* __restrict__ cvec,
    ushort_t* wskip_bf, ushort_t* wres0_bf, ushort_t* wres1_bf,
    ushort_t* wqkv_bf, ushort_t* wproj_bf, ushort_t* xT, uint4* zbuf)
{
    __shared__ float T[64 * 65];
    const int b = blockIdx.x, tid = threadIdx.x;

    if (b >= 2561) {                     // emb_mm: c = emb @ mp_weight(w_emb,gain)^T + 1
        int n = b - 2561;
        const float* e  = emb   + (size_t)n * 768;
        const float* wr = w_emb + (size_t)tid * 768;
        float ss = 0.f, dot = 0.f;
        for (int i = 0; i < 768; i++) {
            float wv = wr[i];
            ss  = fmaf(wv, wv, ss);
            dot = fmaf(e[i], wv, dot);
        }
        float scale = gain_ptr[0] / (EPSV * sqrtf(768.0f) + sqrtf(ss));
        cvec[n * COUT + tid] = dot * scale + 1.0f;
        return;
    }
    if (b == 2560) {                     // zfill
        if (tid < 64) zbuf[tid] = make_uint4(0u, 0u, 0u, 0u);
        return;
    }
    if (b >= 1792) {                     // prep_xT: [n][192][1024] f32 -> [n][1024][192] bf16
        int b2 = b - 1792;
        int n = b2 / 48, rem = b2 % 48;
        int ci0 = (rem / 16) * 64, s0 = (rem & 15) * 64;
#pragma unroll
        for (int i = 0; i < 16; i++) {
            int ch = tid + i * 256; int row = ch >> 6, cc = ch & 63;
            T[row * 65 + cc] = x[((size_t)n * 192 + ci0 + row) * SDIM + s0 + cc];
        }
        __syncthreads();
#pragma unroll
        for (int i = 0; i < 2; i++) {
            int ch = tid + i * 256; int srow = ch >> 3, c8 = ch & 7;
            ushort_t tmp[8];
#pragma unroll
            for (int j = 0; j < 8; j++) tmp[j] = f2bs(T[(c8 * 8 + j) * 65 + srow]);
            *(uint4*)(xT + ((size_t)n * SDIM + s0 + srow) * 192 + ci0 + c8 * 8) = *(uint4*)tmp;
        }
        return;
    }
    // weight-norm branches
    const float* src; ushort_t* dst; int fanin, mode, o;
    if      (b < 256)  { src = w_skip; dst = wskip_bf; fanin = 192;  mode = 0; o = b; }
    else if (b < 512)  { src = w_res0; dst = wres0_bf; fanin = 2304; mode = 1; o = b - 256; }
    else if (b < 768)  { src = w_res1; dst = wres1_bf; fanin = 2304; mode = 1; o = b - 512; }
    else if (b < 1536) { src = w_qkv;  dst = wqkv_bf;  fanin = 256;  mode = 2; o = b - 768; }
    else               { src = w_proj; dst = wproj_bf; fanin = 256;  mode = 0; o = b - 1536; }

    const float* row = src + (size_t)o * fanin;
    float ss = 0.f;
    for (int i = tid; i < fanin; i += 256) { float v = row[i]; ss += v * v; }
    for (int off = 32; off >= 1; off >>= 1) ss += __shfl_down(ss, off);
    int lane = tid & 63, wv = tid >> 6;
    if (lane == 0) T[wv] = ss;
    __syncthreads();
    float tot = T[0] + T[1] + T[2] + T[3];
    float scale = 1.0f / (EPSV * sqrtf((float)fanin) + sqrtf(tot));
    int orow = o;
    if (mode == 2) { int h = o / 192, rem = o % 192; orow = (rem % 3) * 256 + h * 64 + rem / 3; }
    for (int i = tid; i < fanin; i += 256) {
        int kd = i;
        if (mode == 1) { int ci = i / 9; int r9 = i - ci * 9; kd = r9 * 256 + ci; }
        dst[(size_t)orow * fanin + kd] = f2bs(row[i] * scale);
    }
}

// ---------------- fused: x1 = conv1x1(x, wskip); xn = pix_norm(x1); sxT = silu(xn)
__global__ __launch_bounds__(256, 2) void skip_fused(const ushort_t* __restrict__ Wp,
                                                     const ushort_t* __restrict__ xT,
                                                     float* __restrict__ xn,
                                                     ushort_t* __restrict__ sxT)
{
    const int n = blockIdx.z, s0 = blockIdx.x * 32;
    const int tid = threadIdx.x, w = tid >> 6, lane = tid & 63;
    const int tx = lane & 15, quad = lane >> 4;

    __shared__ ushort_t As[256 * 72];
    __shared__ ushort_t Bs[32 * 72];
    __shared__ float csum[4][32];

    f32x4 acc[4][2];
#pragma unroll
    for (int a = 0; a < 4; a++)
#pragma unroll
        for (int b = 0; b < 2; b++) acc[a][b] = (f32x4){0.f, 0.f, 0.f, 0.f};

    for (int k0 = 0; k0 < 192; k0 += 64) {
        __syncthreads();
#pragma unroll
        for (int i = 0; i < 8; i++) {
            int ch = tid + i * 256; int row = ch >> 3, c8 = ch & 7;
            *(uint4*)&As[row * 72 + c8 * 8] = *(const uint4*)(Wp + (size_t)row * 192 + k0 + c8 * 8);
        }
        {
            int row = tid >> 3, c8 = tid & 7;
            *(uint4*)&Bs[row * 72 + c8 * 8] =
                *(const uint4*)(xT + ((size_t)n * SDIM + s0 + row) * 192 + k0 + c8 * 8);
        }
        __syncthreads();
#pragma unroll
        for (int kc = 0; kc < 2; kc++) {
            s16x8 af[4], bf_[2];
#pragma unroll
            for (int mt = 0; mt < 4; mt++) af[mt] = ld16(&As[(w * 64 + mt * 16 + tx) * 72 + kc * 32 + quad * 8]);
#pragma unroll
            for (int nt = 0; nt < 2; nt++) bf_[nt] = ld16(&Bs[(nt * 16 + tx) * 72 + kc * 32 + quad * 8]);
#pragma unroll
            for (int mt = 0; mt < 4; mt++)
#pragma unroll
                for (int nt = 0; nt < 2; nt++)
                    acc[mt][nt] = __builtin_amdgcn_mfma_f32_16x16x32_bf16(af[mt], bf_[nt], acc[mt][nt], 0, 0, 0);
        }
    }

#pragma unroll
    for (int nt = 0; nt < 2; nt++) {
        float s2 = 0.f;
#pragma unroll
        for (int mt = 0; mt < 4; mt++)
#pragma unroll
            for (int r = 0; r < 4; r++) s2 = fmaf(acc[mt][nt][r], acc[mt][nt][r], s2);
        s2 += __shfl_xor(s2, 16); s2 += __shfl_xor(s2, 32);
        if (quad == 0) csum[w][nt * 16 + tx] = s2;
    }
    __syncthreads();
    float f[2];
#pragma unroll
    for (int nt = 0; nt < 2; nt++) {
        int col = nt * 16 + tx;
        float tot = csum[0][col] + csum[1][col] + csum[2][col] + csum[3][col];
        f[nt] = 1.f / (EPSV + sqrtf(tot) * 0.0625f);
    }
    ushort_t* Ls = As;                      // [32 s][264 co]
    float* xb = xn + (size_t)n * COUT * SDIM;
#pragma unroll
    for (int mt = 0; mt < 4; mt++)
#pragma unroll
        for (int r = 0; r < 4; r++) {
            int co = w * 64 + mt * 16 + quad * 4 + r;
#pragma unroll
            for (int nt = 0; nt < 2; nt++) {
                int sp = s0 + nt * 16 + tx;
                float v = acc[mt][nt][r] * f[nt];
                xb[(size_t)co * SDIM + sp] = v;
                Ls[(nt * 16 + tx) * 264 + co] = f2bs(silu_mp(v));
            }
        }
    __syncthreads();
#pragma unroll
    for (int i = 0; i < 4; i++) {
        int ch = tid + i * 256; int row = ch >> 5, c32 = ch & 31;
        *(uint4*)(sxT + ((size_t)n * SDIM + s0 + row) * 256 + c32 * 8) = *(uint4*)&Ls[row * 264 + c32 * 8];
    }
}

// ---------------- bf16 MFMA conv GEMM: glds staging, XOR-swizzled LDS, dbuf,
// 128co x 64s tile, waves 2x2 (wave 64co x 32s), BK=64.  (round-9 proven version)
// MODE 1: res0 -> *cvec, silu, OutT bf16 [n][1024][256] (transposed)
// MODE 2: res1 -> x2 = MPA*xn+MPB*acc; xn fp32 in place; OutT bf16 [n][1024][256]
// MODE 3: proj -> Outf = clip(MPA*RX+MPB*acc) fp32 [n][256][1024]
// MODE 4: qkv  -> fused 64-ch norm; q,k (co0<512) -> OutT = qkT[n][1024][512]
//                 (q scaled 0.125*log2e); v (co0>=512) -> Vout = vbuf[n][256][1024]
template<int KDIM, bool GATHER3, int MODE>
__global__ __launch_bounds__(256, 2) void gemm_glds(const ushort_t* __restrict__ Wp,
                                                    const ushort_t* __restrict__ Bsrc,
                                                    const ushort_t* __restrict__ zbuf,
                                                    float* RX, float* Outf,
                                                    ushort_t* OutT, ushort_t* Vout,
                                                    const float* __restrict__ cvec)
{
    const int n = blockIdx.z, co0 = blockIdx.y * 128, s0 = blockIdx.x * 64;
    const int tid = threadIdx.x, w = tid >> 6, lane = tid & 63;
    const int tx = lane & 15, quad = lane >> 4;
    const int wm = w >> 1, ws = w & 1;
    const int l8 = lane & 7, ld = lane >> 3;
    const int swz = (l8 ^ ld) * 8;

    __shared__ ushort_t SH[2 * 12288];      // stage: A[128][64] + B[64][64] = 24 KB

    const ushort_t* bn = Bsrc + (size_t)n * SDIM * 256;

    auto stageA = [&](int p, int k0) {
        ushort_t* Ab = SH + p * 12288;
#pragma unroll
        for (int j = 0; j < 4; j++) {
            int row0 = w * 32 + j * 8;
            gld16(Wp + (size_t)(co0 + row0 + ld) * KDIM + k0 + swz, Ab + row0 * 64);
        }
    };
    auto stageB = [&](int p, int k0) {
        ushort_t* Bb = SH + p * 12288 + 8192;
        int ci0 = k0, dy = 0, dx = 0;
        if (GATHER3) { int seg = k0 >> 8; ci0 = k0 & 255; int s3 = seg / 3; dy = s3 - 1; dx = seg - s3 * 3 - 1; }
#pragma unroll
        for (int j = 0; j < 2; j++) {
            int row0 = w * 16 + j * 8;
            const ushort_t* g;
            if (GATHER3) {
                int pix = s0 + row0 + ld;
                int h = (pix >> 5) + dy, wx = (pix & 31) + dx;
                bool valid = ((unsigned)h < 32u) && ((unsigned)wx < 32u);
                g = valid ? (bn + (size_t)((h << 5) + wx) * 256 + ci0 + swz) : zbuf;
            } else {
                g = bn + (size_t)(s0 + row0 + ld) * 256 + k0 + swz;
            }
            gld16(g, Bb + row0 * 64);
        }
    };

    f32x4 acc[4][2];
#pragma unroll
    for (int a = 0; a < 4; a++)
#pragma unroll
        for (int b = 0; b < 2; b++) acc[a][b] = (f32x4){0.f, 0.f, 0.f, 0.f};

    constexpr int NK = KDIM / 64;
    stageA(0, 0); stageB(0, 0);
    __syncthreads();

    for (int kt = 0; kt < NK; kt++) {
        int p = kt & 1;
        if (kt + 1 < NK) { stageA(p ^ 1, (kt + 1) * 64); stageB(p ^ 1, (kt + 1) * 64); }
        const ushort_t* Ab = SH + p * 12288;
        const ushort_t* Bb = Ab + 8192;
#pragma unroll
        for (int kc = 0; kc < 2; kc++) {
            int koff = ((kc * 4 + quad) ^ (tx & 7)) * 8;
            s16x8 af[4], bfv[2];
#pragma unroll
            for (int mt = 0; mt < 4; mt++) af[mt]  = ld16(&Ab[(wm * 64 + mt * 16 + tx) * 64 + koff]);
#pragma unroll
            for (int nt = 0; nt < 2; nt++) bfv[nt] = ld16(&Bb[(ws * 32 + nt * 16 + tx) * 64 + koff]);
#pragma unroll
            for (int mt = 0; mt < 4; mt++)
#pragma unroll
                for (int nt = 0; nt < 2; nt++)
                    acc[mt][nt] = __builtin_amdgcn_mfma_f32_16x16x32_bf16(af[mt], bfv[nt], acc[mt][nt], 0, 0, 0);
        }
        __syncthreads();
    }

    if (MODE == 4) {
        float scl[2];
#pragma unroll
        for (int nt = 0; nt < 2; nt++) {
            float s2 = 0.f;
#pragma unroll
            for (int mt = 0; mt < 4; mt++)
#pragma unroll
                for (int r = 0; r < 4; r++) s2 = fmaf(acc[mt][nt][r], acc[mt][nt][r], s2);
            s2 += __shfl_xor(s2, 16); s2 += __shfl_xor(s2, 32);
            float fac = (co0 < 256) ? (0.125f * LOG2E) : 1.0f;
            scl[nt] = fac / (EPSV + sqrtf(s2) * 0.125f);
        }
#pragma unroll
        for (int mt = 0; mt < 4; mt++)
#pragma unroll
            for (int nt = 0; nt < 2; nt++)
#pragma unroll
                for (int r = 0; r < 4; r++) acc[mt][nt][r] *= scl[nt];

        if (co0 < 512) {      // q,k: transposed -> qkT[n][s][512]
            ushort_t* Ls = SH;                  // [64 s][136 co]
#pragma unroll
            for (int mt = 0; mt < 4; mt++)
#pragma unroll
                for (int nt = 0; nt < 2; nt++)
#pragma unroll
                    for (int r = 0; r < 4; r++)
                        Ls[(ws * 32 + nt * 16 + tx) * 136 + wm * 64 + mt * 16 + quad * 4 + r] = f2bs(acc[mt][nt][r]);
            __syncthreads();
#pragma unroll
            for (int i = 0; i < 4; i++) {
                int ch = tid + i * 256; int row = ch >> 4, c16 = ch & 15;
                *(uint4*)(OutT + ((size_t)n * SDIM + s0 + row) * 512 + co0 + c16 * 8) = *(uint4*)&Ls[row * 136 + c16 * 8];
            }
        } else {              // v: [co][s] -> vbuf[n][256][1024]
            ushort_t* Ls = SH;                  // [128 co][72 s]
#pragma unroll
            for (int mt = 0; mt < 4; mt++)
#pragma unroll
                for (int nt = 0; nt < 2; nt++)
#pragma unroll
                    for (int r = 0; r < 4; r++)
                        Ls[(wm * 64 + mt * 16 + quad * 4 + r) * 72 + ws * 32 + nt * 16 + tx] = f2bs(acc[mt][nt][r]);
            __syncthreads();
#pragma unroll
            for (int i = 0; i < 4; i++) {
                int ch = tid + i * 256; int row = ch >> 3, c8 = ch & 7;
                *(uint4*)(Vout + ((size_t)n * 256 + (co0 - 512) + row) * SDIM + s0 + c8 * 8) = *(uint4*)&Ls[row * 72 + c8 * 8];
            }
        }
    }
    if (MODE == 1) {
        float cm[4][4];
#pragma unroll
        for (int mt = 0; mt < 4; mt++)
#pragma unroll
            for (int r = 0; r < 4; r++)
                cm[mt][r] = cvec[n * COUT + co0 + wm * 64 + mt * 16 + quad * 4 + r];
        ushort_t* Ls = SH;                  // [64 s][136 co]
#pragma unroll
        for (int mt = 0; mt < 4; mt++)
#pragma unroll
            for (int nt = 0; nt < 2; nt++)
#pragma unroll
                for (int r = 0; r < 4; r++) {
                    float v = silu_mp(acc[mt][nt][r] * cm[mt][r]);
                    Ls[(ws * 32 + nt * 16 + tx) * 136 + wm * 64 + mt * 16 + quad * 4 + r] = f2bs(v);
                }
        __syncthreads();
#pragma unroll
        for (int i = 0; i < 4; i++) {
            int ch = tid + i * 256; int row = ch >> 4, c16 = ch & 15;
            *(uint4*)(OutT + ((size_t)n * SDIM + s0 + row) * 256 + co0 + c16 * 8) = *(uint4*)&Ls[row * 136 + c16 * 8];
        }
    }
    if (MODE == 2) {
        ushort_t* Ls = SH;                  // [64 s][136 co]
#pragma unroll
        for (int mt = 0; mt < 4; mt++)
#pragma unroll
            for (int r = 0; r < 4; r++) {
                int col = wm * 64 + mt * 16 + quad * 4 + r;
                float* xp = RX + ((size_t)n * COUT + co0 + col) * SDIM + s0 + ws * 32;
#pragma unroll
                for (int nt = 0; nt < 2; nt++) {
                    float v = MPA * xp[nt * 16 + tx] + MPB * acc[mt][nt][r];
                    xp[nt * 16 + tx] = v;
                    Ls[(ws * 32 + nt * 16 + tx) * 136 + col] = f2bs(v);
                }
            }
        __syncthreads();
#pragma unroll
        for (int i = 0; i < 4; i++) {
            int ch = tid + i * 256; int row = ch >> 4, c16 = ch & 15;
            *(uint4*)(OutT + ((size_t)n * SDIM + s0 + row) * 256 + co0 + c16 * 8) = *(uint4*)&Ls[row * 136 + c16 * 8];
        }
    }
    if (MODE == 3) {
#pragma unroll
        for (int mt = 0; mt < 4; mt++)
#pragma unroll
            for (int r = 0; r < 4; r++) {
                int co = co0 + wm * 64 + mt * 16 + quad * 4 + r;
                const float* xp = RX + ((size_t)n * COUT + co) * SDIM + s0 + ws * 32;
                float* op = Outf + ((size_t)n * COUT + co) * SDIM + s0 + ws * 32;
#pragma unroll
                for (int nt = 0; nt < 2; nt++) {
                    float v = MPA * xp[nt * 16 + tx] + MPB * acc[mt][nt][r];
                    op[nt * 16 + tx] = fminf(fmaxf(v, -256.f), 256.f);
                }
            }
    }
}

// ---------------- MFMA flash attention, glds-dbuf K/V + pipelined P.
// S computed TRANSPOSED (mfma(kf,qf)): lane holds 4 consecutive keys per q,
// so P stores are packed ds_write_b64 (8/lane/kt instead of 32 b16).
// Block = 128 q (4 waves x 32 q), grid 512 -> 2 blocks/CU. LDS = 64 KB.
__global__ __launch_bounds__(256, 2) void attn_mfma(const ushort_t* __restrict__ qkT,
                                                    const ushort_t* __restrict__ vbuf,
                                                    ushort_t* __restrict__ aT)
{
    const int n = blockIdx.z, head = blockIdx.y, q0 = blockIdx.x * 128;
    const int tid = threadIdx.x, w = tid >> 6, lane = tid & 63;
    const int tx = lane & 15, quad = lane >> 4;
    const int l8 = lane & 7, ld = lane >> 3;
    const int swz = (l8 ^ ld) * 8;

    __shared__ ushort_t Kst[2][4096];   // [stage][64 key][64 c]
    __shared__ ushort_t Vst[2][4096];   // [stage][64 c][64 key]
    __shared__ ushort_t Pw[8][2048];    // [wave*2+stage][32 q][64 k] chunk-swizzled

    const size_t nb = (size_t)n * SDIM;
    const int qw = q0 + w * 32;
    const ushort_t* kg = qkT + nb * 512 + 256 + head * 64;
    const ushort_t* vg = vbuf + ((size_t)n * 256 + head * 64) * SDIM;

    auto stage = [&](int p, int k0) {
#pragma unroll
        for (int j = 0; j < 2; j++) {
            int row0 = w * 16 + j * 8;
            gld16(kg + (size_t)(k0 + row0 + ld) * 512 + swz, &Kst[p][row0 * 64]);
            gld16(vg + (size_t)(row0 + ld) * SDIM + k0 + swz, &Vst[p][row0 * 64]);
        }
    };
    auto pv_step = [&](int pb, f32x4 (&acco)[2][4]) {
        const ushort_t* Pp = Pw[w * 2 + pb];
#pragma unroll
        for (int kc = 0; kc < 2; kc++) {
            int koff = ((kc * 4 + quad) ^ (tx & 7)) * 8;
            s16x8 pf[2];
#pragma unroll
            for (int mt = 0; mt < 2; mt++)
                pf[mt] = ld16(&Pp[(mt * 16 + tx) * 64 + koff]);
#pragma unroll
            for (int nt = 0; nt < 4; nt++) {
                s16x8 vf = ld16(&Vst[pb][(nt * 16 + tx) * 64 + koff]);
#pragma unroll
                for (int mt = 0; mt < 2; mt++)
                    acco[mt][nt] = __builtin_amdgcn_mfma_f32_16x16x32_bf16(
                        pf[mt], vf, acco[mt][nt], 0, 0, 0);
            }
        }
    };

    // Q frags (q pre-scaled by 0.125*log2e); used as B-operand for S^T
    s16x8 qf[2][2];
#pragma unroll
    for (int mt = 0; mt < 2; mt++)
#pragma unroll
        for (int kc = 0; kc < 2; kc++)
            qf[mt][kc] = ld16(qkT + (nb + qw + mt * 16 + tx) * 512 + head * 64 + kc * 32 + quad * 8);

    f32x4 acco[2][4];
    float lsum[2] = {0.f, 0.f};        // partial row-sum for q = mt*16+tx (this lane's share)
#pragma unroll
    for (int mt = 0; mt < 2; mt++)
#pragma unroll
        for (int nt = 0; nt < 4; nt++) acco[mt][nt] = (f32x4){0.f, 0.f, 0.f, 0.f};

    stage(0, 0);

    for (int kt = 0; kt < 16; kt++) {
        int p = kt & 1;
        if (kt > 0) pv_step(p ^ 1, acco);
        __syncthreads();
        if (kt < 15) stage(p ^ 1, (kt + 1) * 64);

        // S^T = K Q^T: element (key = nt*16+quad*4+r, q = mt*16+tx)
        f32x4 accs[4][2];
#pragma unroll
        for (int nt = 0; nt < 4; nt++)
#pragma unroll
            for (int mt = 0; mt < 2; mt++) accs[nt][mt] = (f32x4){0.f, 0.f, 0.f, 0.f};
#pragma unroll
        for (int kc = 0; kc < 2; kc++) {
            int koff = ((kc * 4 + quad) ^ (tx & 7)) * 8;
#pragma unroll
            for (int nt = 0; nt < 4; nt++) {
                s16x8 kf = ld16(&Kst[p][(nt * 16 + tx) * 64 + koff]);
#pragma unroll
                for (int mt = 0; mt < 2; mt++)
                    accs[nt][mt] = __builtin_amdgcn_mfma_f32_16x16x32_bf16(
                        kf, qf[mt][kc], accs[nt][mt], 0, 0, 0);
            }
        }
        // P = 2^S; 4 consecutive keys per reg -> packed b64 writes into Pw[p]
#pragma unroll
        for (int mt = 0; mt < 2; mt++)
#pragma unroll
            for (int nt = 0; nt < 4; nt++) {
                ushort_t tmp[4];
#pragma unroll
                for (int r = 0; r < 4; r++) {
                    float pv = EXP2F(accs[nt][mt][r]);
                    lsum[mt] += pv;
                    tmp[r] = f2bs(pv);
                }
                int slot = (nt * 2 + (quad >> 1)) ^ (tx & 7);
                int addr = (mt * 16 + tx) * 64 + slot * 8 + (quad & 1) * 4;
                *(uint2*)&Pw[w * 2 + p][addr] = *(uint2*)tmp;
            }
    }
    asm volatile("s_waitcnt lgkmcnt(0)" ::: "memory");
    pv_step(1, acco);

    // row sums: lane holds partial for q=mt*16+tx over its quad's keys; reduce
    // across quads (xor 16,32), then redistribute to O rows q=mt*16+quad*4+r.
    float linv[2][4];
#pragma unroll
    for (int mt = 0; mt < 2; mt++) {
        float l = lsum[mt];
        l += __shfl_xor(l, 16); l += __shfl_xor(l, 32);
#pragma unroll
        for (int r = 0; r < 4; r++)
            linv[mt][r] = 1.0f / __shfl(l, quad * 4 + r);
    }

    // O stage (swizzled, O rows q=mt*16+quad*4+r, cols c=nt*16+tx) -> global
#pragma unroll
    for (int mt = 0; mt < 2; mt++)
#pragma unroll
        for (int r = 0; r < 4; r++) {
            int row = mt * 16 + quad * 4 + r;
            int rx = row & 7;
#pragma unroll
            for (int nt = 0; nt < 4; nt++) {
                int slot = (nt * 2 + (tx >> 3)) ^ rx;
                Pw[w * 2][row * 64 + slot * 8 + (tx & 7)] = f2bs(acco[mt][nt][r] * linv[mt][r]);
            }
        }
    asm volatile("s_waitcnt lgkmcnt(0)" ::: "memory");
    ushort_t* dst = aT + (nb + qw) * 256 + head * 64;
#pragma unroll
    for (int i = 0; i < 4; i++) {
        int ch = lane + i * 64; int row = ch >> 3, c8 = ch & 7;
        *(uint4*)(dst + (size_t)row * 256 + c8 * 8) = *(uint4*)&Pw[w * 2][row * 64 + (c8 ^ (row & 7)) * 8];
    }
}

extern "C" void kernel_launch(void* const* d_in, const int* in_sizes, int n_in,
                              void* d_out, int out_size, void* d_ws, size_t ws_size,
                              hipStream_t stream)
{
    const float* x      = (const float*)d_in[0];
    const float* emb    = (const float*)d_in[1];
    const float* w_skip = (const float*)d_in[2];
    const float* w_res0 = (const float*)d_in[3];
    const float* w_res1 = (const float*)d_in[4];
    const float* w_emb  = (const float*)d_in[5];
    const float* e_gain = (const float*)d_in[6];
    const float* w_qkv  = (const float*)d_in[7];
    const float* w_proj = (const float*)d_in[8];
    float* out = (float*)d_out;

    char* p = (char*)d_ws;
    auto alloc = [&](size_t bytes) { void* r = (void*)p; p += (bytes + 255) & ~(size_t)255; return r; };
    ushort_t* wskip_bf = (ushort_t*)alloc(256 * 192 * 2);
    ushort_t* wres0_bf = (ushort_t*)alloc(256 * 2304 * 2);
    ushort_t* wres1_bf = (ushort_t*)alloc(256 * 2304 * 2);
    ushort_t* wqkv_bf  = (ushort_t*)alloc(768 * 256 * 2);
    ushort_t* wproj_bf = (ushort_t*)alloc(256 * 256 * 2);
    float*    cvec     = (float*)alloc(16 * 256 * 4);
    ushort_t* zbuf     = (ushort_t*)alloc(1024);
    ushort_t* xT   = (ushort_t*)alloc((size_t)16 * 1024 * 192 * 2);
    ushort_t* sxT  = (ushort_t*)alloc((size_t)16 * 1024 * 256 * 2);
    ushort_t* ysT  = (ushort_t*)alloc((size_t)16 * 1024 * 256 * 2);
    ushort_t* x2T  = (ushort_t*)alloc((size_t)16 * 1024 * 256 * 2);
    ushort_t* aT   = (ushort_t*)alloc((size_t)16 * 1024 * 256 * 2);
    float*    xn   = (float*)alloc((size_t)16 * 256 * 1024 * 4);
    ushort_t* qkT  = (ushort_t*)alloc((size_t)16 * 1024 * 512 * 2);
    ushort_t* vbuf = (ushort_t*)alloc((size_t)16 * 256 * 1024 * 2);

    // fused prologue: weight norms + x transpose + zbuf + emb_mm
    prep_all<<<2577, 256, 0, stream>>>(w_skip, w_res0, w_res1, w_qkv, w_proj, x,
                                       emb, w_emb, e_gain, cvec,
                                       wskip_bf, wres0_bf, wres1_bf, wqkv_bf, wproj_bf,
                                       xT, (uint4*)zbuf);

    skip_fused<<<dim3(32, 1, 16), 256, 0, stream>>>(wskip_bf, xT, xn, sxT);
    gemm_glds<2304, true, 1><<<dim3(16, 2, 16), 256, 0, stream>>>(wres0_bf, sxT, zbuf, nullptr, nullptr, ysT, nullptr, cvec);
    gemm_glds<2304, true, 2><<<dim3(16, 2, 16), 256, 0, stream>>>(wres1_bf, ysT, zbuf, xn, nullptr, x2T, nullptr, nullptr);
    gemm_glds<256, false, 4><<<dim3(16, 6, 16), 256, 0, stream>>>(wqkv_bf, x2T, zbuf, nullptr, nullptr, qkT, vbuf, nullptr);
    attn_mfma<<<dim3(8, 4, 16), 256, 0, stream>>>(qkT, vbuf, aT);
    gemm_glds<256, false, 3><<<dim3(16, 2, 16), 256, 0, stream>>>(wproj_bf, aT, zbuf, xn, out, nullptr, nullptr, nullptr);
}